// Round 8
// baseline (202.103 us; speedup 1.0000x reference)
//
#include <hip/hip_runtime.h>
#include <hip/hip_bf16.h>
#include <cstdint>

typedef unsigned short u16;
typedef __attribute__((ext_vector_type(8))) short short8;
typedef __attribute__((ext_vector_type(4))) float f32x4;

__device__ __forceinline__ u16 f2b(float f) {
  uint32_t u = __float_as_uint(f);
  u += 0x7fffu + ((u >> 16) & 1u);   // RNE to bf16
  return (u16)(u >> 16);
}
__device__ __forceinline__ float b2f(u16 b) {
  return __uint_as_float(((uint32_t)b) << 16);
}
__device__ __forceinline__ uint32_t pk2bf(float a, float b) {
  __hip_bfloat162 t = __float22bfloat162_rn(make_float2(a, b));
  return *(uint32_t*)&t;   // packed {lo=a, hi=b}
}

// ---------------------------------------------------------------------------
// Cast fp32 inputs feeding MFMA to bf16. Also zeroes the 128 flash combine
// counters (runs strictly before flash in-stream; ws is poisoned 0xAA).
// ---------------------------------------------------------------------------
__global__ __launch_bounds__(256) void cast_all(
    const float* __restrict__ Q, const float* __restrict__ K,
    const float* __restrict__ Wq, const float* __restrict__ Wk,
    const float* __restrict__ Wv, const float* __restrict__ Wo,
    u16* __restrict__ xq, u16* __restrict__ xk,
    u16* __restrict__ wq, u16* __restrict__ wk,
    u16* __restrict__ wv, u16* __restrict__ wo,
    uint32_t* __restrict__ cnt) {
  int g = blockIdx.x * 256 + threadIdx.x;
  if (g < 128) cnt[g] = 0;
  const float* src; u16* dst; int off;
  if      (g <  524288) { src = Q;  dst = xq; off = g; }
  else if (g < 1048576) { src = K;  dst = xk; off = g -  524288; }
  else if (g < 1310720) { src = Wq; dst = wq; off = g - 1048576; }
  else if (g < 1572864) { src = Wk; dst = wk; off = g - 1310720; }
  else if (g < 1835008) { src = Wv; dst = wv; off = g - 1572864; }
  else                  { src = Wo; dst = wo; off = g - 1835008; }
  float4 v = reinterpret_cast<const float4*>(src)[off];
  ushort4 o4;
  o4.x = f2b(v.x); o4.y = f2b(v.y); o4.z = f2b(v.z); o4.w = f2b(v.w);
  reinterpret_cast<ushort4*>(dst)[off] = o4;
}

// ---------------------------------------------------------------------------
// Merged projection GEMMs, 128x64 tile, BK=32, 4 waves (2x2), wave 64x32.
// (r6-proven; XCD-contiguous swizzle kept — measured neutral, harmless.)
// ---------------------------------------------------------------------------
__global__ __launch_bounds__(256) void gemm3(
    const u16* __restrict__ xq, const u16* __restrict__ xk,
    const u16* __restrict__ wq, const u16* __restrict__ wk,
    const u16* __restrict__ wv,
    const float* __restrict__ bq, const float* __restrict__ bk,
    const float* __restrict__ bv,
    u16* __restrict__ qb, u16* __restrict__ kb, u16* __restrict__ vT) {
  __shared__ __align__(16) u16 sA[128 * 40];
  __shared__ __align__(16) u16 sB[64 * 40];
  const int t = threadIdx.x, blk = blockIdx.x, z = blockIdx.y;
  const int xcd = blk & 7, lid = blk >> 3;   // 32 blocks per XCD slice
  const u16 *A, *B; const float* bias; u16* C; int ldC, mbase, nbase; bool brow;
  if (z == 0)      { A = xq; B = wq; bias = bq; C = qb; ldC = 1024;
                     mbase = (xcd * 2 + (lid >> 4)) * 128; nbase = (lid & 15) * 64; brow = false; }
  else if (z == 1) { A = xk; B = wk; bias = bk; C = kb; ldC = 1024;
                     mbase = (xcd * 2 + (lid >> 4)) * 128; nbase = (lid & 15) * 64; brow = false; }
  else             { A = wv; B = xk; bias = bv; C = vT; ldC = 2048;
                     mbase = xcd * 128; nbase = lid * 64; brow = true; }
  const int lane = t & 63, wid = t >> 6;
  const int wy = wid >> 1, wx = wid & 1;
  const int m = lane & 15, quad = lane >> 4;

  const int arow = t >> 1, acb = (t & 1) * 16;
  const int brow_ = t >> 2, bcb = (t & 3) * 8;
  const u16* gA = A + (mbase + arow) * 1024 + acb;
  const u16* gB = B + (nbase + brow_) * 1024 + bcb;

  uint4 ra0 = *(const uint4*)(gA);
  uint4 ra1 = *(const uint4*)(gA + 8);
  uint4 rb0 = *(const uint4*)(gB);

  f32x4 acc[4][2];
#pragma unroll
  for (int i = 0; i < 4; i++)
#pragma unroll
    for (int j = 0; j < 2; j++) acc[i][j] = (f32x4){0.f, 0.f, 0.f, 0.f};

  for (int kb_ = 0; kb_ < 32; ++kb_) {
    __syncthreads();
    *(uint4*)(&sA[arow * 40 + acb])     = ra0;
    *(uint4*)(&sA[arow * 40 + acb + 8]) = ra1;
    *(uint4*)(&sB[brow_ * 40 + bcb])    = rb0;
    if (kb_ < 31) {
      ra0 = *(const uint4*)(gA + (kb_ + 1) * 32);
      ra1 = *(const uint4*)(gA + (kb_ + 1) * 32 + 8);
      rb0 = *(const uint4*)(gB + (kb_ + 1) * 32);
    }
    __syncthreads();
    short8 af[4], bf[2];
#pragma unroll
    for (int mi = 0; mi < 4; mi++)
      af[mi] = *(const short8*)(&sA[(wy * 64 + mi * 16 + m) * 40 + quad * 8]);
#pragma unroll
    for (int ni = 0; ni < 2; ni++)
      bf[ni] = *(const short8*)(&sB[(wx * 32 + ni * 16 + m) * 40 + quad * 8]);
#pragma unroll
    for (int mi = 0; mi < 4; mi++)
#pragma unroll
      for (int ni = 0; ni < 2; ni++)
        acc[mi][ni] = __builtin_amdgcn_mfma_f32_16x16x32_bf16(
            af[mi], bf[ni], acc[mi][ni], 0, 0, 0);
  }

#pragma unroll
  for (int mi = 0; mi < 4; mi++)
#pragma unroll
    for (int ni = 0; ni < 2; ni++) {
      const int col = nbase + wx * 32 + ni * 16 + m;
      const float bcol = brow ? 0.f : bias[col];
#pragma unroll
      for (int r = 0; r < 4; r++) {
        const int row = mbase + wy * 64 + mi * 16 + quad * 4 + r;
        const float bval = brow ? bias[row] : bcol;
        C[row * ldC + col] = f2b(acc[mi][ni][r] + bval);
      }
    }
}

// ---------------------------------------------------------------------------
// Final GEMM: out = Res + relu(A*B^T + bias), M=2048 N=1024, fp32 out.
// 64x64 tile, 512 blocks (2/CU). (r6-proven.)
// ---------------------------------------------------------------------------
__global__ __launch_bounds__(256) void gemm_out(
    const u16* __restrict__ A, const u16* __restrict__ B,
    const float* __restrict__ bias, const u16* __restrict__ Res,
    float* __restrict__ out) {
  __shared__ __align__(16) u16 sA[64 * 40];
  __shared__ __align__(16) u16 sB[64 * 40];
  const int t = threadIdx.x, blk = blockIdx.x;
  const int xcd = blk & 7, lid = blk >> 3;   // 64 blocks per XCD slice
  const int mbase = (xcd * 4 + (lid >> 4)) * 64, nbase = (lid & 15) * 64;
  const int lane = t & 63, wid = t >> 6;
  const int wy = wid >> 1, wx = wid & 1;
  const int m = lane & 15, quad = lane >> 4;
  const int srow = t >> 2, scb = (t & 3) * 8;
  const u16* gA = A + (mbase + srow) * 1024 + scb;
  const u16* gB = B + (nbase + srow) * 1024 + scb;
  uint4 ra = *(const uint4*)gA;
  uint4 rb = *(const uint4*)gB;

  f32x4 acc[2][2];
#pragma unroll
  for (int i = 0; i < 2; i++)
#pragma unroll
    for (int j = 0; j < 2; j++) acc[i][j] = (f32x4){0.f, 0.f, 0.f, 0.f};

  for (int kb_ = 0; kb_ < 32; ++kb_) {
    __syncthreads();
    *(uint4*)(&sA[srow * 40 + scb]) = ra;
    *(uint4*)(&sB[srow * 40 + scb]) = rb;
    if (kb_ < 31) {
      ra = *(const uint4*)(gA + (kb_ + 1) * 32);
      rb = *(const uint4*)(gB + (kb_ + 1) * 32);
    }
    __syncthreads();
    short8 af[2], bf[2];
#pragma unroll
    for (int mi = 0; mi < 2; mi++)
      af[mi] = *(const short8*)(&sA[(wy * 32 + mi * 16 + m) * 40 + quad * 8]);
#pragma unroll
    for (int ni = 0; ni < 2; ni++)
      bf[ni] = *(const short8*)(&sB[(wx * 32 + ni * 16 + m) * 40 + quad * 8]);
#pragma unroll
    for (int mi = 0; mi < 2; mi++)
#pragma unroll
      for (int ni = 0; ni < 2; ni++)
        acc[mi][ni] = __builtin_amdgcn_mfma_f32_16x16x32_bf16(
            af[mi], bf[ni], acc[mi][ni], 0, 0, 0);
  }

#pragma unroll
  for (int mi = 0; mi < 2; mi++)
#pragma unroll
    for (int ni = 0; ni < 2; ni++) {
      const int col = nbase + wx * 32 + ni * 16 + m;
      const float bcol = bias[col];
#pragma unroll
      for (int r = 0; r < 4; r++) {
        const int row = mbase + wy * 32 + mi * 16 + quad * 4 + r;
        out[row * 1024 + col] =
            b2f(Res[row * 1024 + col]) + fmaxf(acc[mi][ni][r] + bcol, 0.f);
      }
    }
}

// ---------------------------------------------------------------------------
// Flash attention v6 = r7 kernel + fused last-arriver combine.
// After storing po/lp partials each block releases (fence) and bumps a
// per-(qt,h) counter; the 4th arriver acquires and performs the combine for
// its 256 q-rows: ob = bf16(q + (sum O_s)/(sum l_s * 32)), scramble-stored
// (row = h*128 + q/16, col = (q%16)*64 + d). Removes the combine dispatch.
// ---------------------------------------------------------------------------
__global__ __launch_bounds__(256, 2) void flash(
    const u16* __restrict__ q, const u16* __restrict__ k,
    const u16* __restrict__ vT, u16* __restrict__ po, float* __restrict__ lp,
    uint32_t* __restrict__ cnt, const u16* __restrict__ qb,
    u16* __restrict__ ob) {
  __shared__ __align__(16) u16 sK[64 * 72];
  __shared__ __align__(16) u16 sV[64 * 72];     // [dim][key]
  __shared__ __align__(16) u16 sP[4 * 64 * 72]; // per-wave [q(64)][key]
  const int t = threadIdx.x;
  const int qt = blockIdx.x, h = blockIdx.y, sp = blockIdx.z;
  const int lane = t & 63, wid = t >> 6;
  const int m = lane & 15, quad = lane >> 4;
  const int colbase = h * 64;
  const int pbase = wid * 4608;  // 64*72 per wave
  const int kbase = sp * 512;    // 4 splits x 512 keys
  const int qwave = qt * 256 + wid * 64;

  short8 aq[4][2];   // B-operand: lane holds Q[q=mi*16+m][d=g*32+quad*8+j]
#pragma unroll
  for (int mi = 0; mi < 4; mi++)
#pragma unroll
    for (int g = 0; g < 2; g++)
      aq[mi][g] = *(const short8*)(
          &q[(qwave + mi * 16 + m) * 1024 + colbase + g * 32 + quad * 8]);

  f32x4 o[4][4];
  float lpart[4] = {0.f, 0.f, 0.f, 0.f};
#pragma unroll
  for (int mi = 0; mi < 4; mi++)
#pragma unroll
    for (int nt = 0; nt < 4; nt++) o[mi][nt] = (f32x4){0.f, 0.f, 0.f, 0.f};

  const int srow = t >> 2, scb = (t & 3) * 16;
  const u16* gK = k + (kbase + srow) * 1024 + colbase + scb;
  const u16* gV = vT + (colbase + srow) * 2048 + kbase + scb;

  uint4 rk0 = *(const uint4*)(gK), rk1 = *(const uint4*)(gK + 8);
  uint4 rv0 = *(const uint4*)(gV), rv1 = *(const uint4*)(gV + 8);

  uint32_t* sP32 = (uint32_t*)sP;

  for (int kt = 0; kt < 8; ++kt) {
    __syncthreads();
    *(uint4*)(&sK[srow * 72 + scb])     = rk0;
    *(uint4*)(&sK[srow * 72 + scb + 8]) = rk1;
    *(uint4*)(&sV[srow * 72 + scb])     = rv0;
    *(uint4*)(&sV[srow * 72 + scb + 8]) = rv1;
    if (kt < 7) {
      rk0 = *(const uint4*)(gK + (kt + 1) * 65536);
      rk1 = *(const uint4*)(gK + (kt + 1) * 65536 + 8);
      rv0 = *(const uint4*)(gV + (kt + 1) * 64);
      rv1 = *(const uint4*)(gV + (kt + 1) * 64 + 8);
    }
    __syncthreads();

    // S^T tiles: D[key=nt*16+quad*4+r][q=mi*16+m], raw logits
#pragma unroll
    for (int nt = 0; nt < 4; nt++) {
      short8 bk0 = *(const short8*)(&sK[(nt * 16 + m) * 72 + quad * 8]);
      short8 bk1 = *(const short8*)(&sK[(nt * 16 + m) * 72 + 32 + quad * 8]);
#pragma unroll
      for (int mi = 0; mi < 4; mi++) {
        f32x4 st = (f32x4){0.f, 0.f, 0.f, 0.f};
        st = __builtin_amdgcn_mfma_f32_16x16x32_bf16(bk0, aq[mi][0], st, 0, 0, 0);
        st = __builtin_amdgcn_mfma_f32_16x16x32_bf16(bk1, aq[mi][1], st, 0, 0, 0);
        // p = exp(s - 16) (fixed shift; no running max needed)
        float p0 = __expf(st[0] - 16.0f);
        float p1 = __expf(st[1] - 16.0f);
        float p2 = __expf(st[2] - 16.0f);
        float p3 = __expf(st[3] - 16.0f);
        lpart[mi] += (p0 + p1) + (p2 + p3);
        const int pa_ = pbase + (mi * 16 + m) * 72 + nt * 16 + quad * 4;
        sP32[pa_ >> 1]       = pk2bf(p0, p1);
        sP32[(pa_ >> 1) + 1] = pk2bf(p2, p3);
      }
    }

    // O += P V   (A-operand read of sP: lane holds P[q=mi*16+m][key=g*32+quad*8+j])
    short8 pa[4][2];
#pragma unroll
    for (int mi = 0; mi < 4; mi++)
#pragma unroll
      for (int g = 0; g < 2; g++)
        pa[mi][g] = *(const short8*)(&sP[pbase + (mi * 16 + m) * 72 + g * 32 + quad * 8]);
#pragma unroll
    for (int nt = 0; nt < 4; nt++) {
      short8 bv0 = *(const short8*)(&sV[(nt * 16 + m) * 72 + quad * 8]);
      short8 bv1 = *(const short8*)(&sV[(nt * 16 + m) * 72 + 32 + quad * 8]);
#pragma unroll
      for (int mi = 0; mi < 4; mi++) {
        o[mi][nt] = __builtin_amdgcn_mfma_f32_16x16x32_bf16(pa[mi][0], bv0, o[mi][nt], 0, 0, 0);
        o[mi][nt] = __builtin_amdgcn_mfma_f32_16x16x32_bf16(pa[mi][1], bv1, o[mi][nt], 0, 0, 0);
      }
    }
  }

  // l: per-lane partial covers keys {nt*16+quad*4+r}; reduce over quads.
#pragma unroll
  for (int mi = 0; mi < 4; mi++) {
    float l = lpart[mi];
    l += __shfl_xor(l, 16);
    l += __shfl_xor(l, 32);
    if (quad == 0)
      lp[(sp * 16 + h) * 2048 + qwave + mi * 16 + m] = l;
  }

#pragma unroll
  for (int mi = 0; mi < 4; mi++)
#pragma unroll
    for (int r = 0; r < 4; r++) {
      const int qg = qwave + mi * 16 + quad * 4 + r;
      const int base = ((sp * 16 + h) * 2048 + qg) * 64;
#pragma unroll
      for (int nt = 0; nt < 4; nt++)
        po[base + nt * 16 + m] = f2b(o[mi][nt][r]);
    }

  // ---- last-arriver combine for this (qt,h) ----
  __syncthreads();                       // all waves' po/lp stores issued
  __shared__ uint32_t s_old;
  if (t == 0) {
    __threadfence();                     // release: partials visible device-wide
    s_old = atomicAdd(&cnt[qt * 16 + h], 1u);
  }
  __syncthreads();
  if (s_old == 3u) {                     // 4th arriver: all splits done
    __threadfence();                     // acquire
    const int dq = (t & 15) * 4;
#pragma unroll
    for (int qi = 0; qi < 16; qi++) {
      const int qg = qt * 256 + (t >> 4) * 16 + qi;
      float a0 = 0.f, a1 = 0.f, a2 = 0.f, a3 = 0.f, l = 0.f;
#pragma unroll
      for (int s = 0; s < 4; s++) {
        const ushort4 p4 =
            *(const ushort4*)&po[(((s * 16 + h) * 2048 + qg) * 64) + dq];
        a0 += b2f(p4.x); a1 += b2f(p4.y); a2 += b2f(p4.z); a3 += b2f(p4.w);
        l += lp[(s * 16 + h) * 2048 + qg];
      }
      const float inv = 1.0f / (l * 32.0f);
      const ushort4 q4 = *(const ushort4*)&qb[qg * 1024 + h * 64 + dq];
      ushort4 o4;
      o4.x = f2b(b2f(q4.x) + a0 * inv);
      o4.y = f2b(b2f(q4.y) + a1 * inv);
      o4.z = f2b(b2f(q4.z) + a2 * inv);
      o4.w = f2b(b2f(q4.w) + a3 * inv);
      *(ushort4*)&ob[(h * 128 + (qg >> 4)) * 1024 + (qg & 15) * 64 + dq] = o4;
    }
  }
}

// ---------------------------------------------------------------------------
extern "C" void kernel_launch(void* const* d_in, const int* in_sizes, int n_in,
                              void* d_out, int out_size, void* d_ws, size_t ws_size,
                              hipStream_t stream) {
  const float* Q  = (const float*)d_in[0];
  const float* K  = (const float*)d_in[1];
  const float* Wq = (const float*)d_in[2];
  const float* bq = (const float*)d_in[3];
  const float* Wk = (const float*)d_in[4];
  const float* bk = (const float*)d_in[5];
  const float* Wv = (const float*)d_in[6];
  const float* bv = (const float*)d_in[7];
  const float* Wo = (const float*)d_in[8];
  const float* bo = (const float*)d_in[9];
  float* out = (float*)d_out;

  u16* ws = (u16*)d_ws;            // 256 MB ws; flat layout
  u16* xq  = ws;                   // 2M u16
  u16* xk  = xq  + 2097152;        // 2M
  u16* wqb = xk  + 2097152;        // 1M
  u16* wkb = wqb + 1048576;        // 1M
  u16* wvb = wkb + 1048576;        // 1M
  u16* wob = wvb + 1048576;        // 1M
  u16* qb  = wob + 1048576;        // 2M
  u16* kb  = qb  + 2097152;        // 2M
  u16* vT  = kb  + 2097152;        // 2M  (v projected TRANSPOSED [1024][2048])
  u16* ob  = vT  + 2097152;        // 2M  (attention out, scrambled)
  u16* po  = ob  + 2097152;        // 8M  (4 splits x 16 h x 2048 q x 64 d)
  float* lp = (float*)(po + 8388608);      // 4x16x2048 fp32
  uint32_t* cnt = (uint32_t*)(lp + 131072); // 128 combine counters

  cast_all<<<8192, 256, 0, stream>>>(Q, K, Wq, Wk, Wv, Wo, xq, xk, wqb, wkb,
                                     wvb, wob, cnt);

  gemm3<<<dim3(256, 3), 256, 0, stream>>>(xq, xk, wqb, wkb, wvb, bq, bk, bv, qb, kb, vT);

  flash<<<dim3(8, 16, 4), 256, 0, stream>>>(qb, kb, vT, po, lp, cnt, qb, ob);

  gemm_out<<<512, 256, 0, stream>>>(ob, wob, bo, ob, out);
}

// Round 9
// 162.874 us; speedup vs baseline: 1.2409x; 1.2409x over previous
//
#include <hip/hip_runtime.h>
#include <hip/hip_bf16.h>
#include <cstdint>

typedef unsigned short u16;
typedef __attribute__((ext_vector_type(8))) short short8;
typedef __attribute__((ext_vector_type(4))) float f32x4;

__device__ __forceinline__ u16 f2b(float f) {
  uint32_t u = __float_as_uint(f);
  u += 0x7fffu + ((u >> 16) & 1u);   // RNE to bf16
  return (u16)(u >> 16);
}
__device__ __forceinline__ float b2f(u16 b) {
  return __uint_as_float(((uint32_t)b) << 16);
}
__device__ __forceinline__ uint32_t pk2bf(float a, float b) {
  __hip_bfloat162 t = __float22bfloat162_rn(make_float2(a, b));
  return *(uint32_t*)&t;   // packed {lo=a, hi=b}
}

// ---------------------------------------------------------------------------
// Cast fp32 inputs feeding MFMA to bf16. (r7-proven.)
// ---------------------------------------------------------------------------
__global__ __launch_bounds__(256) void cast_all(
    const float* __restrict__ Q, const float* __restrict__ K,
    const float* __restrict__ Wq, const float* __restrict__ Wk,
    const float* __restrict__ Wv, const float* __restrict__ Wo,
    u16* __restrict__ xq, u16* __restrict__ xk,
    u16* __restrict__ wq, u16* __restrict__ wk,
    u16* __restrict__ wv, u16* __restrict__ wo) {
  int g = blockIdx.x * 256 + threadIdx.x;
  const float* src; u16* dst; int off;
  if      (g <  524288) { src = Q;  dst = xq; off = g; }
  else if (g < 1048576) { src = K;  dst = xk; off = g -  524288; }
  else if (g < 1310720) { src = Wq; dst = wq; off = g - 1048576; }
  else if (g < 1572864) { src = Wk; dst = wk; off = g - 1310720; }
  else if (g < 1835008) { src = Wv; dst = wv; off = g - 1572864; }
  else                  { src = Wo; dst = wo; off = g - 1835008; }
  float4 v = reinterpret_cast<const float4*>(src)[off];
  ushort4 o4;
  o4.x = f2b(v.x); o4.y = f2b(v.y); o4.z = f2b(v.z); o4.w = f2b(v.w);
  reinterpret_cast<ushort4*>(dst)[off] = o4;
}

// ---------------------------------------------------------------------------
// Merged projection GEMMs, 128x64 tile, BK=64 (halved barrier count vs r7),
// 4 waves (2x2), wave 64x32. XCD-contiguous swizzle kept (neutral, harmless).
// z=0: qb = xq*wq^T + bq          (M=2048,N=1024)
// z=1: kb = xk*wk^T + bk          (M=2048,N=1024)
// z=2: vT = wv*xk^T + bv[row]     (M=1024,N=2048)  <- V produced TRANSPOSED
// ---------------------------------------------------------------------------
__global__ __launch_bounds__(256) void gemm3(
    const u16* __restrict__ xq, const u16* __restrict__ xk,
    const u16* __restrict__ wq, const u16* __restrict__ wk,
    const u16* __restrict__ wv,
    const float* __restrict__ bq, const float* __restrict__ bk,
    const float* __restrict__ bv,
    u16* __restrict__ qb, u16* __restrict__ kb, u16* __restrict__ vT) {
  __shared__ __align__(16) u16 sA[128 * 72];
  __shared__ __align__(16) u16 sB[64 * 72];
  const int t = threadIdx.x, blk = blockIdx.x, z = blockIdx.y;
  const int xcd = blk & 7, lid = blk >> 3;   // 32 blocks per XCD slice
  const u16 *A, *B; const float* bias; u16* C; int ldC, mbase, nbase; bool brow;
  if (z == 0)      { A = xq; B = wq; bias = bq; C = qb; ldC = 1024;
                     mbase = (xcd * 2 + (lid >> 4)) * 128; nbase = (lid & 15) * 64; brow = false; }
  else if (z == 1) { A = xk; B = wk; bias = bk; C = kb; ldC = 1024;
                     mbase = (xcd * 2 + (lid >> 4)) * 128; nbase = (lid & 15) * 64; brow = false; }
  else             { A = wv; B = xk; bias = bv; C = vT; ldC = 2048;
                     mbase = xcd * 128; nbase = lid * 64; brow = true; }
  const int lane = t & 63, wid = t >> 6;
  const int wy = wid >> 1, wx = wid & 1;
  const int m = lane & 15, quad = lane >> 4;

  // staging (BK=64): A: 4 x uint4 per thread, B: 2 x uint4
  const int arow = t >> 1, acb = (t & 1) * 32;
  const int brow_ = t >> 2, bcb = (t & 3) * 16;
  const u16* gA = A + (mbase + arow) * 1024 + acb;
  const u16* gB = B + (nbase + brow_) * 1024 + bcb;

  uint4 ra0 = *(const uint4*)(gA);
  uint4 ra1 = *(const uint4*)(gA + 8);
  uint4 ra2 = *(const uint4*)(gA + 16);
  uint4 ra3 = *(const uint4*)(gA + 24);
  uint4 rb0 = *(const uint4*)(gB);
  uint4 rb1 = *(const uint4*)(gB + 8);

  f32x4 acc[4][2];
#pragma unroll
  for (int i = 0; i < 4; i++)
#pragma unroll
    for (int j = 0; j < 2; j++) acc[i][j] = (f32x4){0.f, 0.f, 0.f, 0.f};

  for (int kb_ = 0; kb_ < 16; ++kb_) {
    __syncthreads();
    *(uint4*)(&sA[arow * 72 + acb])      = ra0;
    *(uint4*)(&sA[arow * 72 + acb + 8])  = ra1;
    *(uint4*)(&sA[arow * 72 + acb + 16]) = ra2;
    *(uint4*)(&sA[arow * 72 + acb + 24]) = ra3;
    *(uint4*)(&sB[brow_ * 72 + bcb])     = rb0;
    *(uint4*)(&sB[brow_ * 72 + bcb + 8]) = rb1;
    if (kb_ < 15) {
      ra0 = *(const uint4*)(gA + (kb_ + 1) * 64);
      ra1 = *(const uint4*)(gA + (kb_ + 1) * 64 + 8);
      ra2 = *(const uint4*)(gA + (kb_ + 1) * 64 + 16);
      ra3 = *(const uint4*)(gA + (kb_ + 1) * 64 + 24);
      rb0 = *(const uint4*)(gB + (kb_ + 1) * 64);
      rb1 = *(const uint4*)(gB + (kb_ + 1) * 64 + 8);
    }
    __syncthreads();
    short8 af[4][2], bf[2][2];
#pragma unroll
    for (int mi = 0; mi < 4; mi++)
#pragma unroll
      for (int ks = 0; ks < 2; ks++)
        af[mi][ks] = *(const short8*)(
            &sA[(wy * 64 + mi * 16 + m) * 72 + ks * 32 + quad * 8]);
#pragma unroll
    for (int ni = 0; ni < 2; ni++)
#pragma unroll
      for (int ks = 0; ks < 2; ks++)
        bf[ni][ks] = *(const short8*)(
            &sB[(wx * 32 + ni * 16 + m) * 72 + ks * 32 + quad * 8]);
#pragma unroll
    for (int ks = 0; ks < 2; ks++)
#pragma unroll
      for (int mi = 0; mi < 4; mi++)
#pragma unroll
        for (int ni = 0; ni < 2; ni++)
          acc[mi][ni] = __builtin_amdgcn_mfma_f32_16x16x32_bf16(
              af[mi][ks], bf[ni][ks], acc[mi][ni], 0, 0, 0);
  }

#pragma unroll
  for (int mi = 0; mi < 4; mi++)
#pragma unroll
    for (int ni = 0; ni < 2; ni++) {
      const int col = nbase + wx * 32 + ni * 16 + m;
      const float bcol = brow ? 0.f : bias[col];
#pragma unroll
      for (int r = 0; r < 4; r++) {
        const int row = mbase + wy * 64 + mi * 16 + quad * 4 + r;
        const float bval = brow ? bias[row] : bcol;
        C[row * ldC + col] = f2b(acc[mi][ni][r] + bval);
      }
    }
}

// ---------------------------------------------------------------------------
// Final GEMM: out = Res + relu(A*B^T + bias), M=2048 N=1024, fp32 out.
// 64x64 tile, BK=64, 512 blocks (2/CU).
// ---------------------------------------------------------------------------
__global__ __launch_bounds__(256) void gemm_out(
    const u16* __restrict__ A, const u16* __restrict__ B,
    const float* __restrict__ bias, const u16* __restrict__ Res,
    float* __restrict__ out) {
  __shared__ __align__(16) u16 sA[64 * 72];
  __shared__ __align__(16) u16 sB[64 * 72];
  const int t = threadIdx.x, blk = blockIdx.x;
  const int xcd = blk & 7, lid = blk >> 3;   // 64 blocks per XCD slice
  const int mbase = (xcd * 4 + (lid >> 4)) * 64, nbase = (lid & 15) * 64;
  const int lane = t & 63, wid = t >> 6;
  const int wy = wid >> 1, wx = wid & 1;
  const int m = lane & 15, quad = lane >> 4;
  const int srow = t >> 2, scb = (t & 3) * 16;
  const u16* gA = A + (mbase + srow) * 1024 + scb;
  const u16* gB = B + (nbase + srow) * 1024 + scb;
  uint4 ra0 = *(const uint4*)(gA), ra1 = *(const uint4*)(gA + 8);
  uint4 rb0 = *(const uint4*)(gB), rb1 = *(const uint4*)(gB + 8);

  f32x4 acc[2][2];
#pragma unroll
  for (int i = 0; i < 2; i++)
#pragma unroll
    for (int j = 0; j < 2; j++) acc[i][j] = (f32x4){0.f, 0.f, 0.f, 0.f};

  for (int kb_ = 0; kb_ < 16; ++kb_) {
    __syncthreads();
    *(uint4*)(&sA[srow * 72 + scb])     = ra0;
    *(uint4*)(&sA[srow * 72 + scb + 8]) = ra1;
    *(uint4*)(&sB[srow * 72 + scb])     = rb0;
    *(uint4*)(&sB[srow * 72 + scb + 8]) = rb1;
    if (kb_ < 15) {
      ra0 = *(const uint4*)(gA + (kb_ + 1) * 64);
      ra1 = *(const uint4*)(gA + (kb_ + 1) * 64 + 8);
      rb0 = *(const uint4*)(gB + (kb_ + 1) * 64);
      rb1 = *(const uint4*)(gB + (kb_ + 1) * 64 + 8);
    }
    __syncthreads();
    short8 af[2][2], bf[2][2];
#pragma unroll
    for (int mi = 0; mi < 2; mi++)
#pragma unroll
      for (int ks = 0; ks < 2; ks++)
        af[mi][ks] = *(const short8*)(
            &sA[(wy * 32 + mi * 16 + m) * 72 + ks * 32 + quad * 8]);
#pragma unroll
    for (int ni = 0; ni < 2; ni++)
#pragma unroll
      for (int ks = 0; ks < 2; ks++)
        bf[ni][ks] = *(const short8*)(
            &sB[(wx * 32 + ni * 16 + m) * 72 + ks * 32 + quad * 8]);
#pragma unroll
    for (int ks = 0; ks < 2; ks++)
#pragma unroll
      for (int mi = 0; mi < 2; mi++)
#pragma unroll
        for (int ni = 0; ni < 2; ni++)
          acc[mi][ni] = __builtin_amdgcn_mfma_f32_16x16x32_bf16(
              af[mi][ks], bf[ni][ks], acc[mi][ni], 0, 0, 0);
  }

#pragma unroll
  for (int mi = 0; mi < 2; mi++)
#pragma unroll
    for (int ni = 0; ni < 2; ni++) {
      const int col = nbase + wx * 32 + ni * 16 + m;
      const float bcol = bias[col];
#pragma unroll
      for (int r = 0; r < 4; r++) {
        const int row = mbase + wy * 32 + mi * 16 + quad * 4 + r;
        out[row * 1024 + col] =
            b2f(Res[row * 1024 + col]) + fmaxf(acc[mi][ni][r] + bcol, 0.f);
      }
    }
}

// ---------------------------------------------------------------------------
// Flash attention (r7-proven): 64 q-rows/wave (mi=4), 256 q/block, grid
// 8x16x4 = 512 blocks = exactly 2/CU. Fixed-shift softmax (raw-logit quirk),
// S^T operand-swap, sP round-trip. Emits bf16 partial O + fp32 partial l.
// ---------------------------------------------------------------------------
__global__ __launch_bounds__(256, 2) void flash(
    const u16* __restrict__ q, const u16* __restrict__ k,
    const u16* __restrict__ vT, u16* __restrict__ po, float* __restrict__ lp) {
  __shared__ __align__(16) u16 sK[64 * 72];
  __shared__ __align__(16) u16 sV[64 * 72];     // [dim][key]
  __shared__ __align__(16) u16 sP[4 * 64 * 72]; // per-wave [q(64)][key]
  const int t = threadIdx.x;
  const int qt = blockIdx.x, h = blockIdx.y, sp = blockIdx.z;
  const int lane = t & 63, wid = t >> 6;
  const int m = lane & 15, quad = lane >> 4;
  const int colbase = h * 64;
  const int pbase = wid * 4608;  // 64*72 per wave
  const int kbase = sp * 512;    // 4 splits x 512 keys
  const int qwave = qt * 256 + wid * 64;

  short8 aq[4][2];   // B-operand: lane holds Q[q=mi*16+m][d=g*32+quad*8+j]
#pragma unroll
  for (int mi = 0; mi < 4; mi++)
#pragma unroll
    for (int g = 0; g < 2; g++)
      aq[mi][g] = *(const short8*)(
          &q[(qwave + mi * 16 + m) * 1024 + colbase + g * 32 + quad * 8]);

  f32x4 o[4][4];
  float lpart[4] = {0.f, 0.f, 0.f, 0.f};
#pragma unroll
  for (int mi = 0; mi < 4; mi++)
#pragma unroll
    for (int nt = 0; nt < 4; nt++) o[mi][nt] = (f32x4){0.f, 0.f, 0.f, 0.f};

  const int srow = t >> 2, scb = (t & 3) * 16;
  const u16* gK = k + (kbase + srow) * 1024 + colbase + scb;
  const u16* gV = vT + (colbase + srow) * 2048 + kbase + scb;

  uint4 rk0 = *(const uint4*)(gK), rk1 = *(const uint4*)(gK + 8);
  uint4 rv0 = *(const uint4*)(gV), rv1 = *(const uint4*)(gV + 8);

  uint32_t* sP32 = (uint32_t*)sP;

  for (int kt = 0; kt < 8; ++kt) {
    __syncthreads();
    *(uint4*)(&sK[srow * 72 + scb])     = rk0;
    *(uint4*)(&sK[srow * 72 + scb + 8]) = rk1;
    *(uint4*)(&sV[srow * 72 + scb])     = rv0;
    *(uint4*)(&sV[srow * 72 + scb + 8]) = rv1;
    if (kt < 7) {
      rk0 = *(const uint4*)(gK + (kt + 1) * 65536);
      rk1 = *(const uint4*)(gK + (kt + 1) * 65536 + 8);
      rv0 = *(const uint4*)(gV + (kt + 1) * 64);
      rv1 = *(const uint4*)(gV + (kt + 1) * 64 + 8);
    }
    __syncthreads();

    // S^T tiles: D[key=nt*16+quad*4+r][q=mi*16+m], raw logits
#pragma unroll
    for (int nt = 0; nt < 4; nt++) {
      short8 bk0 = *(const short8*)(&sK[(nt * 16 + m) * 72 + quad * 8]);
      short8 bk1 = *(const short8*)(&sK[(nt * 16 + m) * 72 + 32 + quad * 8]);
#pragma unroll
      for (int mi = 0; mi < 4; mi++) {
        f32x4 st = (f32x4){0.f, 0.f, 0.f, 0.f};
        st = __builtin_amdgcn_mfma_f32_16x16x32_bf16(bk0, aq[mi][0], st, 0, 0, 0);
        st = __builtin_amdgcn_mfma_f32_16x16x32_bf16(bk1, aq[mi][1], st, 0, 0, 0);
        // p = exp(s - 16) (fixed shift; no running max needed)
        float p0 = __expf(st[0] - 16.0f);
        float p1 = __expf(st[1] - 16.0f);
        float p2 = __expf(st[2] - 16.0f);
        float p3 = __expf(st[3] - 16.0f);
        lpart[mi] += (p0 + p1) + (p2 + p3);
        const int pa_ = pbase + (mi * 16 + m) * 72 + nt * 16 + quad * 4;
        sP32[pa_ >> 1]       = pk2bf(p0, p1);
        sP32[(pa_ >> 1) + 1] = pk2bf(p2, p3);
      }
    }

    // O += P V   (A-operand read of sP: lane holds P[q=mi*16+m][key=g*32+quad*8+j])
    short8 pa[4][2];
#pragma unroll
    for (int mi = 0; mi < 4; mi++)
#pragma unroll
      for (int g = 0; g < 2; g++)
        pa[mi][g] = *(const short8*)(&sP[pbase + (mi * 16 + m) * 72 + g * 32 + quad * 8]);
#pragma unroll
    for (int nt = 0; nt < 4; nt++) {
      short8 bv0 = *(const short8*)(&sV[(nt * 16 + m) * 72 + quad * 8]);
      short8 bv1 = *(const short8*)(&sV[(nt * 16 + m) * 72 + 32 + quad * 8]);
#pragma unroll
      for (int mi = 0; mi < 4; mi++) {
        o[mi][nt] = __builtin_amdgcn_mfma_f32_16x16x32_bf16(pa[mi][0], bv0, o[mi][nt], 0, 0, 0);
        o[mi][nt] = __builtin_amdgcn_mfma_f32_16x16x32_bf16(pa[mi][1], bv1, o[mi][nt], 0, 0, 0);
      }
    }
  }

  // l: per-lane partial covers keys {nt*16+quad*4+r}; reduce over quads.
#pragma unroll
  for (int mi = 0; mi < 4; mi++) {
    float l = lpart[mi];
    l += __shfl_xor(l, 16);
    l += __shfl_xor(l, 32);
    if (quad == 0)
      lp[(sp * 16 + h) * 2048 + qwave + mi * 16 + m] = l;
  }

#pragma unroll
  for (int mi = 0; mi < 4; mi++)
#pragma unroll
    for (int r = 0; r < 4; r++) {
      const int qg = qwave + mi * 16 + quad * 4 + r;
      const int base = ((sp * 16 + h) * 2048 + qg) * 64;
#pragma unroll
      for (int nt = 0; nt < 4; nt++)
        po[base + nt * 16 + m] = f2b(o[mi][nt][r]);
    }
}

// ---------------------------------------------------------------------------
// Combine splits: ob = bf16( q + (sum O_s)/(sum l_s * 32) ), scramble-stored
// per the reference's raw reshape: row = h*128 + q/16, col = (q%16)*64 + d.
// ---------------------------------------------------------------------------
__global__ __launch_bounds__(256) void combine(
    const u16* __restrict__ po, const float* __restrict__ lp,
    const u16* __restrict__ qb, u16* __restrict__ ob) {
  const int idx = blockIdx.x * 256 + threadIdx.x;   // 524288 total
  const int dq = idx & 15, qg = (idx >> 4) & 2047, h = idx >> 15;
  float acc0 = 0.f, acc1 = 0.f, acc2 = 0.f, acc3 = 0.f, l = 0.f;
#pragma unroll
  for (int s = 0; s < 4; s++) {
    const ushort4 p4 = *(const ushort4*)&po[(((s * 16 + h) * 2048 + qg) * 64) + dq * 4];
    acc0 += b2f(p4.x); acc1 += b2f(p4.y); acc2 += b2f(p4.z); acc3 += b2f(p4.w);
    l += lp[(s * 16 + h) * 2048 + qg];
  }
  const float inv = 1.0f / (l * 32.0f);
  const ushort4 q4 = *(const ushort4*)&qb[qg * 1024 + h * 64 + dq * 4];
  ushort4 o4;
  o4.x = f2b(b2f(q4.x) + acc0 * inv);
  o4.y = f2b(b2f(q4.y) + acc1 * inv);
  o4.z = f2b(b2f(q4.z) + acc2 * inv);
  o4.w = f2b(b2f(q4.w) + acc3 * inv);
  *(ushort4*)&ob[(h * 128 + (qg >> 4)) * 1024 + (qg & 15) * 64 + dq * 4] = o4;
}

// ---------------------------------------------------------------------------
extern "C" void kernel_launch(void* const* d_in, const int* in_sizes, int n_in,
                              void* d_out, int out_size, void* d_ws, size_t ws_size,
                              hipStream_t stream) {
  const float* Q  = (const float*)d_in[0];
  const float* K  = (const float*)d_in[1];
  const float* Wq = (const float*)d_in[2];
  const float* bq = (const float*)d_in[3];
  const float* Wk = (const float*)d_in[4];
  const float* bk = (const float*)d_in[5];
  const float* Wv = (const float*)d_in[6];
  const float* bv = (const float*)d_in[7];
  const float* Wo = (const float*)d_in[8];
  const float* bo = (const float*)d_in[9];
  float* out = (float*)d_out;

  u16* ws = (u16*)d_ws;            // 256 MB ws; flat layout
  u16* xq  = ws;                   // 2M u16
  u16* xk  = xq  + 2097152;        // 2M
  u16* wqb = xk  + 2097152;        // 1M
  u16* wkb = wqb + 1048576;        // 1M
  u16* wvb = wkb + 1048576;        // 1M
  u16* wob = wvb + 1048576;        // 1M
  u16* qb  = wob + 1048576;        // 2M
  u16* kb  = qb  + 2097152;        // 2M
  u16* vT  = kb  + 2097152;        // 2M  (v projected TRANSPOSED [1024][2048])
  u16* ob  = vT  + 2097152;        // 2M  (attention out, scrambled)
  u16* po  = ob  + 2097152;        // 8M  (4 splits x 16 h x 2048 q x 64 d)
  float* lp = (float*)(po + 8388608);  // 4x16x2048 fp32

  cast_all<<<8192, 256, 0, stream>>>(Q, K, Wq, Wk, Wv, Wo, xq, xk, wqb, wkb, wvb, wob);

  gemm3<<<dim3(256, 3), 256, 0, stream>>>(xq, xk, wqb, wkb, wvb, bq, bk, bv, qb, kb, vT);

  flash<<<dim3(8, 16, 4), 256, 0, stream>>>(qb, kb, vT, po, lp);

  combine<<<2048, 256, 0, stream>>>(po, lp, qb, ob);

  gemm_out<<<512, 256, 0, stream>>>(ob, wob, bo, ob, out);
}